// Round 3
// baseline (217.541 us; speedup 1.0000x reference)
//
#include <hip/hip_runtime.h>
#include <hip/hip_cooperative_groups.h>

// B=2, N=1024, Fin=64, Fout=32 — all fp32.
// Degenerate-score GAT, single cooperative kernel:
//   Phase A (all 512 blocks): projections -> vvT (transposed [b][f][j]), p, q1, q2
//   grid.sync
//   Phase B (blocks 0,1): per-batch softmax sums (r_raw, Z, slo, shi)
//   Phase C (blocks 2..511, concurrent with B): acc = adj_row . vvT
//   grid.sync
//   Epilogue: att from (p | r_raw/Z) + 0.5*(att+acc), leaky, store.

#define ALPHA 0.01f
namespace cg = cooperative_groups;

__device__ __forceinline__ float leaky(float x){ return x >= 0.f ? x : ALPHA*x; }

__global__ __launch_bounds__(256, 2) void gat_fused(
    const float* __restrict__ inp, const float* __restrict__ kin,
    const float* __restrict__ vin, const float* __restrict__ adj,
    const float* __restrict__ W,   const float* __restrict__ Wk,
    const float* __restrict__ Wv,  const float* __restrict__ a,
    float* __restrict__ vvT, float* __restrict__ p,
    float* __restrict__ q1,  float* __restrict__ q2,
    float* __restrict__ rraw, float* __restrict__ Zv,
    float* __restrict__ slo,  float* __restrict__ shi,
    float* __restrict__ out)
{
    cg::grid_group grid = cg::this_grid();
    const int tid  = threadIdx.x;
    const int bid  = blockIdx.x;
    const int lane = tid & 63;
    const int f    = lane & 31;
    const int h    = lane >> 5;   // half selector within wave
    const int rl   = tid >> 6;    // 0..3 (row/unit within block)

    __shared__ float sm[8*32*2 + 8];   // B: r/v partials + z; C-extra: reuse

    // ---------------- Phase A: projections, 4 rows/block ----------------
    {
        int row = bid*4 + rl;                    // 0..2047
        const float* xr = inp + row*64 + h*32;
        const float* kr = kin + row*64 + h*32;
        const float* vr = vin + row*64 + h*32;
        const float* Wb  = W  + (h*32)*32 + f;
        const float* Wkb = Wk + (h*32)*32 + f;
        const float* Wvb = Wv + (h*32)*32 + f;
        float ha = 0.f, ka = 0.f, va = 0.f;
        #pragma unroll
        for (int c = 0; c < 32; c++){
            float x = xr[c], k = kr[c], v = vr[c];
            ha += x * Wb [c*32];
            ka += k * Wkb[c*32];
            va += v * Wvb[c*32];
        }
        // combine the two c-halves (partner lane^32)
        ha += __shfl_xor(ha, 32, 64);
        ka += __shfl_xor(ka, 32, 64);
        va += __shfl_xor(va, 32, 64);
        int b = row >> 10, i = row & 1023;
        if (h == 0) vvT[(b*32 + f)*1024 + i] = va;
        float a1 = a[f], a2 = a[32+f];
        float pv  = ha*(a1+a2);
        float q1v = ka*a1;
        float q2v = ka*a2;
        #pragma unroll
        for (int m = 16; m; m >>= 1){
            pv  += __shfl_xor(pv , m, 64);
            q1v += __shfl_xor(q1v, m, 64);
            q2v += __shfl_xor(q2v, m, 64);
        }
        if (lane == 0){ p[row] = pv; q1[row] = q1v; q2[row] = q2v; }
    }

    grid.sync();

    float acc   = 0.f;   // phase-C main accumulator
    float acc_e = 0.f;   // extra-unit accumulator (blocks 2..9, tid<32)

    if (bid < 2){
        // ---------------- Phase B: per-batch softmax sums ----------------
        // scores (shared by all rows i>=512): s_j = leaky(q1[(2j)%N] + q2[(2j+1)%N])
        // No max-subtraction: |s| is O(1), exp is safe.
        const int b = bid;
        const int g = tid >> 5;                  // 0..7, j-slice [g*128, g*128+128)
        const float* q1b = q1 + b*1024;
        const float* q2b = q2 + b*1024;
        const float4* vt = (const float4*)(vvT + (b*32 + f)*1024) + g*32;
        float racc = 0.f, vsum = 0.f, zacc = 0.f;
        #pragma unroll 4
        for (int tq = 0; tq < 32; tq++){
            int j = g*128 + tq*4;
            float e0 = __expf(leaky(q1b[(2*j  ) & 1023] + q2b[(2*j+1) & 1023]));
            float e1 = __expf(leaky(q1b[(2*j+2) & 1023] + q2b[(2*j+3) & 1023]));
            float e2 = __expf(leaky(q1b[(2*j+4) & 1023] + q2b[(2*j+5) & 1023]));
            float e3 = __expf(leaky(q1b[(2*j+6) & 1023] + q2b[(2*j+7) & 1023]));
            float4 v4 = vt[tq];
            racc += e0*v4.x + e1*v4.y + e2*v4.z + e3*v4.w;
            vsum += v4.x + v4.y + v4.z + v4.w;
            zacc += e0 + e1 + e2 + e3;
        }
        sm[g*32 + f]       = racc;
        sm[256 + g*32 + f] = vsum;
        if (f == 0) sm[512 + g] = zacc;
        __syncthreads();
        if (tid < 32){
            float rs = 0.f, ls = 0.f, hs = 0.f;
            #pragma unroll
            for (int gg = 0; gg < 8; gg++){
                rs += sm[gg*32 + tid];
                float vs = sm[256 + gg*32 + tid];
                if (gg < 4) ls += vs; else hs += vs;
            }
            rraw[b*32 + tid] = rs;
            slo [b*32 + tid] = ls;
            shi [b*32 + tid] = hs;
            if (tid == 0){
                float z = 0.f;
                #pragma unroll
                for (int gg = 0; gg < 8; gg++) z += sm[512 + gg];
                Zv[b] = z;
            }
        }
    } else {
        // ---------------- Phase C: adj . vvT, 4 units/block ----------------
        int u = (bid - 2)*4 + rl;                // 0..2039
        int b = u >> 10, i = u & 1023;
        int jh = (tid >> 5) & 1;                 // j-half
        const float4* arow = (const float4*)(adj + i*1024 + jh*512);
        const float4* vt   = (const float4*)(vvT + (b*32 + f)*1024 + jh*512);
        #pragma unroll 4
        for (int t = 0; t < 128; t++){
            float4 a4 = arow[t], v4 = vt[t];
            acc += a4.x*v4.x + a4.y*v4.y + a4.z*v4.z + a4.w*v4.w;
        }
        if (bid < 10){
            // extra units 2040..2047 (one per block 2..9), j split 8 ways
            int ue = 2040 + (bid - 2);
            int be = ue >> 10, ie = ue & 1023;   // be=1, ie in [1016,1024)
            int js = tid >> 5;                   // 0..7
            const float4* ar2 = (const float4*)(adj + ie*1024 + js*128);
            const float4* vt2 = (const float4*)(vvT + (be*32 + f)*1024 + js*128);
            float pe = 0.f;
            #pragma unroll 4
            for (int t = 0; t < 32; t++){
                float4 a4 = ar2[t], v4 = vt2[t];
                pe += a4.x*v4.x + a4.y*v4.y + a4.z*v4.z + a4.w*v4.w;
            }
            sm[js*32 + f] = pe;
            __syncthreads();
            if (tid < 32){
                #pragma unroll
                for (int gg = 0; gg < 8; gg++) acc_e += sm[gg*32 + tid];
            }
        }
    }

    grid.sync();

    // ---------------- Epilogue ----------------
    if (bid >= 2){
        float accs = acc + __shfl_xor(acc, 32, 64);   // combine j-halves
        int u = (bid - 2)*4 + rl;
        int b = u >> 10, i = u & 1023;
        if (h == 0){
            float att;
            if (i < 512){
                // two distinct scores per row: leaky(p[2i]), leaky(p[2i+1])
                float s0 = leaky(p[b*1024 + 2*i]);
                float s1 = leaky(p[b*1024 + 2*i + 1]);
                float e0 = __expf(s0), e1 = __expf(s1);
                att = (e0*slo[b*32+f] + e1*shi[b*32+f]) / (512.f*(e0 + e1));
            } else {
                att = rraw[b*32+f] / Zv[b];
            }
            out[u*32 + f] = leaky(0.5f*(att + accs));
        }
        if (bid < 10 && tid < 32){
            int ue = 2040 + (bid - 2);
            int be = ue >> 10;                    // ie >= 512 always -> r path
            float att = rraw[be*32 + tid] / Zv[be];
            out[ue*32 + tid] = leaky(0.5f*(att + acc_e));
        }
    }
}

extern "C" void kernel_launch(void* const* d_in, const int* in_sizes, int n_in,
                              void* d_out, int out_size, void* d_ws, size_t ws_size,
                              hipStream_t stream)
{
    const float* inp = (const float*)d_in[0];
    const float* kin = (const float*)d_in[1];
    const float* vin = (const float*)d_in[2];
    const float* adj = (const float*)d_in[3];
    const float* W   = (const float*)d_in[4];
    const float* Wk  = (const float*)d_in[5];
    const float* Wv  = (const float*)d_in[6];
    const float* a   = (const float*)d_in[7];
    float* out = (float*)d_out;

    float* ws   = (float*)d_ws;
    float* vvT  = ws;             // 65536 floats  [b][f][j]
    float* p    = ws + 65536;     // 2048
    float* q1   = ws + 67584;     // 2048
    float* q2   = ws + 69632;     // 2048
    float* rraw = ws + 71680;     // 64
    float* Zv   = ws + 71744;     // 2
    float* slo  = ws + 71746;     // 64 (alignment fine: float)
    float* shi  = ws + 71810;     // 64
    (void)in_sizes; (void)n_in; (void)out_size; (void)ws_size;

    void* kargs[] = {
        (void*)&inp, (void*)&kin, (void*)&vin, (void*)&adj,
        (void*)&W, (void*)&Wk, (void*)&Wv, (void*)&a,
        (void*)&vvT, (void*)&p, (void*)&q1, (void*)&q2,
        (void*)&rraw, (void*)&Zv, (void*)&slo, (void*)&shi,
        (void*)&out
    };
    hipLaunchCooperativeKernel((void*)gat_fused, dim3(512), dim3(256),
                               kargs, 0, stream);
}

// Round 4
// 118.970 us; speedup vs baseline: 1.8285x; 1.8285x over previous
//
#include <hip/hip_runtime.h>

// B=2, N=1024, Fin=64, Fout=32 — all fp32.
// Degenerate-score GAT, 3 plain kernels (no cooperative launch):
//   K1 k_proj: projections -> vv (j-major [b][j][f]), p, q1, q2
//   K2 k_soft: per-batch softmax sums -> r (normalized), slo, shi, w01
//   K3 k_out : dot(adj_row, vv) per (b,i,f) + epilogue
// K3 design notes: float4-over-features vv loads (coalesced 128B per octet,
// broadcast across 4 row-lanes), float4 adj broadcast, 4 independent FMA
// chains per thread, j split 8 ways -> shfl_xor(32) + 2KB LDS reduce.
// 512 blocks = 2/CU = 8 waves/CU for latency hiding.

#define ALPHA 0.01f

__device__ __forceinline__ float leaky(float x){ return x >= 0.f ? x : ALPHA*x; }

// ---------------- K1: projections + row scalars -------------------------
// 512 blocks x 256 thr; 4 rows/block; wave = 1 row; lanes split c-halves.
__global__ __launch_bounds__(256) void k_proj(
    const float* __restrict__ inp, const float* __restrict__ kin,
    const float* __restrict__ vin, const float* __restrict__ W,
    const float* __restrict__ Wk,  const float* __restrict__ Wv,
    const float* __restrict__ a,
    float* __restrict__ vv, float* __restrict__ p,
    float* __restrict__ q1, float* __restrict__ q2)
{
    int tid  = threadIdx.x;
    int lane = tid & 63;
    int f    = lane & 31;
    int h    = lane >> 5;          // c-half selector
    int rl   = tid >> 6;           // 0..3
    int row  = blockIdx.x*4 + rl;  // 0..2047
    const float* xr = inp + row*64 + h*32;
    const float* kr = kin + row*64 + h*32;
    const float* vr = vin + row*64 + h*32;
    const float* Wb  = W  + (h*32)*32 + f;
    const float* Wkb = Wk + (h*32)*32 + f;
    const float* Wvb = Wv + (h*32)*32 + f;
    float ha = 0.f, ka = 0.f, va = 0.f;
    #pragma unroll
    for (int c = 0; c < 32; c++){
        float x = xr[c], k = kr[c], v = vr[c];
        ha += x * Wb [c*32];
        ka += k * Wkb[c*32];
        va += v * Wvb[c*32];
    }
    ha += __shfl_xor(ha, 32);
    ka += __shfl_xor(ka, 32);
    va += __shfl_xor(va, 32);
    if (h == 0) vv[row*32 + f] = va;        // j-major layout
    float a1 = a[f], a2 = a[32+f];
    float pv  = ha*(a1+a2);
    float q1v = ka*a1;
    float q2v = ka*a2;
    #pragma unroll
    for (int m = 16; m; m >>= 1){
        pv  += __shfl_xor(pv , m);
        q1v += __shfl_xor(q1v, m);
        q2v += __shfl_xor(q2v, m);
    }
    if (lane == 0){ p[row] = pv; q1[row] = q1v; q2[row] = q2v; }
}

// ---------------- K2: per-batch softmax + reductions --------------------
// grid = 2 blocks x 256 thr. Produces r (normalized att@vv row for i>=512),
// slo/shi (half-sums of vv), w01 (pair weights for i<512).
__global__ __launch_bounds__(256) void k_soft(
    const float* __restrict__ p,  const float* __restrict__ q1,
    const float* __restrict__ q2, const float* __restrict__ vv,
    float* __restrict__ r, float* __restrict__ slo, float* __restrict__ shi,
    float* __restrict__ w01)
{
    int b = blockIdx.x;
    int tid = threadIdx.x;
    __shared__ float e[1024];
    __shared__ float red[768];
    __shared__ float wred[8];
    const float* q1b = q1 + b*1024;
    const float* q2b = q2 + b*1024;

    float tloc[4]; float mloc = -1e30f;
    #pragma unroll
    for (int t = 0; t < 4; t++){
        int j  = tid + t*256;
        int j0 = (2*j)   & 1023;
        int j1 = (2*j+1) & 1023;
        float ts = leaky(q1b[j0] + q2b[j1]);
        tloc[t] = ts; mloc = fmaxf(mloc, ts);
    }
    #pragma unroll
    for (int off = 32; off; off >>= 1) mloc = fmaxf(mloc, __shfl_down(mloc, off, 64));
    if ((tid&63) == 0) wred[tid>>6] = mloc;
    __syncthreads();
    float m = fmaxf(fmaxf(wred[0],wred[1]), fmaxf(wred[2],wred[3]));

    float ssum = 0.f;
    #pragma unroll
    for (int t = 0; t < 4; t++){
        float ev = __expf(tloc[t]-m);
        e[tid + t*256] = ev;
        ssum += ev;
    }
    #pragma unroll
    for (int off = 32; off; off >>= 1) ssum += __shfl_down(ssum, off, 64);
    if ((tid&63) == 0) wred[4 + (tid>>6)] = ssum;
    __syncthreads();
    float invZ = 1.f/(wred[4]+wred[5]+wred[6]+wred[7]);

    int f = tid&31, g = tid>>5;
    const float* vvb = vv + b*32768;
    float racc=0.f, lacc=0.f, hacc=0.f;
    for (int j = g; j < 1024; j += 8){
        float vf = vvb[j*32+f];
        racc += e[j]*vf;
        if (j < 512) lacc += vf; else hacc += vf;
    }
    red[g*32+f]=racc; red[256+g*32+f]=lacc; red[512+g*32+f]=hacc;
    __syncthreads();
    if (g == 0){
        float rs=0.f, ls=0.f, hs=0.f;
        #pragma unroll
        for (int gg = 0; gg < 8; gg++){
            rs += red[gg*32+f];
            ls += red[256+gg*32+f];
            hs += red[512+gg*32+f];
        }
        r  [b*32+f] = rs*invZ;
        slo[b*32+f] = ls;
        shi[b*32+f] = hs;
    }
    const float* pb = p + b*1024;
    for (int i = tid; i < 512; i += 256){
        float s0 = leaky(pb[2*i]);
        float s1 = leaky(pb[2*i+1]);
        float mm = fmaxf(s0,s1);
        float e0 = __expf(s0-mm), e1 = __expf(s1-mm);
        float d  = 1.f/(512.f*(e0+e1));
        w01[(b*512+i)*2  ] = e0*d;
        w01[(b*512+i)*2+1] = e1*d;
    }
}

// ---------------- K3: adj@vv + combine + leaky --------------------------
// 512 blocks x 256 thr. block = (batch b, 4 rows). thread = (o=f/4, rr, js).
// Each thread: 128 j's, 4 independent FMA chains on a float4 accumulator.
__global__ __launch_bounds__(256) void k_out(
    const float* __restrict__ adj, const float* __restrict__ vv,
    const float* __restrict__ r,   const float* __restrict__ slo,
    const float* __restrict__ shi, const float* __restrict__ w01,
    float* __restrict__ out)
{
    __shared__ float red[4][4][32];   // [wave][row][feature]
    int tid = threadIdx.x;
    int b   = blockIdx.x & 1;
    int it  = blockIdx.x >> 1;        // 0..255
    int o   = tid & 7;                // feature quad
    int rr  = (tid >> 3) & 3;         // row within block
    int js  = tid >> 5;               // 0..7, j-slice of 128
    int i   = it*4 + rr;

    const float4* ap = (const float4*)(adj + i*1024 + js*128);
    const float*  vb = vv + b*32768 + o*4 + js*128*32;
    float4 acc = make_float4(0.f, 0.f, 0.f, 0.f);
    #pragma unroll 4
    for (int m = 0; m < 32; m++){
        float4 a4 = ap[m];
        const float* v0p = vb + (m*4+0)*32;
        float4 v0 = *(const float4*)(v0p);
        float4 v1 = *(const float4*)(v0p + 32);
        float4 v2 = *(const float4*)(v0p + 64);
        float4 v3 = *(const float4*)(v0p + 96);
        acc.x += a4.x*v0.x; acc.y += a4.x*v0.y; acc.z += a4.x*v0.z; acc.w += a4.x*v0.w;
        acc.x += a4.y*v1.x; acc.y += a4.y*v1.y; acc.z += a4.y*v1.z; acc.w += a4.y*v1.w;
        acc.x += a4.z*v2.x; acc.y += a4.z*v2.y; acc.z += a4.z*v2.z; acc.w += a4.z*v2.w;
        acc.x += a4.w*v3.x; acc.y += a4.w*v3.y; acc.z += a4.w*v3.z; acc.w += a4.w*v3.w;
    }
    // combine js pairs within wave (lane ^ 32)
    acc.x += __shfl_xor(acc.x, 32);
    acc.y += __shfl_xor(acc.y, 32);
    acc.z += __shfl_xor(acc.z, 32);
    acc.w += __shfl_xor(acc.w, 32);
    if ((tid & 32) == 0){
        int w = tid >> 6;
        red[w][rr][o*4+0] = acc.x;
        red[w][rr][o*4+1] = acc.y;
        red[w][rr][o*4+2] = acc.z;
        red[w][rr][o*4+3] = acc.w;
    }
    __syncthreads();
    if (tid < 128){
        int rr2 = tid >> 5, f = tid & 31;
        float d = red[0][rr2][f] + red[1][rr2][f] + red[2][rr2][f] + red[3][rr2][f];
        int i2 = it*4 + rr2;
        float att;
        if (i2 < 512){
            float w0 = w01[(b*512+i2)*2];
            float w1 = w01[(b*512+i2)*2+1];
            att = w0*slo[b*32+f] + w1*shi[b*32+f];
        } else {
            att = r[b*32+f];
        }
        out[(b*1024+i2)*32 + f] = leaky(0.5f*(att + d));
    }
}

extern "C" void kernel_launch(void* const* d_in, const int* in_sizes, int n_in,
                              void* d_out, int out_size, void* d_ws, size_t ws_size,
                              hipStream_t stream)
{
    const float* inp = (const float*)d_in[0];
    const float* kin = (const float*)d_in[1];
    const float* vin = (const float*)d_in[2];
    const float* adj = (const float*)d_in[3];
    const float* W   = (const float*)d_in[4];
    const float* Wk  = (const float*)d_in[5];
    const float* Wv  = (const float*)d_in[6];
    const float* a   = (const float*)d_in[7];
    float* out = (float*)d_out;

    float* ws  = (float*)d_ws;
    float* vv  = ws;            // 65536 floats, [b][j][f]
    float* p   = ws + 65536;    // 2048
    float* q1  = ws + 67584;    // 2048
    float* q2  = ws + 69632;    // 2048
    float* r   = ws + 71680;    // 64
    float* slo = ws + 71744;    // 64
    float* shi = ws + 71808;    // 64
    float* w01 = ws + 71872;    // 2048
    (void)in_sizes; (void)n_in; (void)out_size; (void)ws_size;

    hipLaunchKernelGGL(k_proj, dim3(512), dim3(256), 0, stream,
                       inp, kin, vin, W, Wk, Wv, a, vv, p, q1, q2);
    hipLaunchKernelGGL(k_soft, dim3(2), dim3(256), 0, stream,
                       p, q1, q2, vv, r, slo, shi, w01);
    hipLaunchKernelGGL(k_out, dim3(512), dim3(256), 0, stream,
                       adj, vv, r, slo, shi, w01, out);
}

// Round 5
// 94.948 us; speedup vs baseline: 2.2912x; 1.2530x over previous
//
#include <hip/hip_runtime.h>

// B=2, N=1024, Fin=64, Fout=32 — all fp32.
// Degenerate-score GAT, 2 kernels:
//   K1 k_proj : projections -> vv (j-major [b][j][f]), p, q1, q2
//   K2 k_fused: per-block e[1024]/Z staging (LDS) + adj.vv dot + fused
//               softmax reductions (racc=e.vv, vs=Sum vv lo/hi) + epilogue.
// Each k_fused block already streams the full vv batch slice for its adj
// rows, so the softmax-weighted reductions ride along for ~free; this
// deletes the old 2-CU K2 kernel and one graph node/gap.

#define ALPHA 0.01f

__device__ __forceinline__ float leaky(float x){ return x >= 0.f ? x : ALPHA*x; }

// ---------------- K1: projections + row scalars -------------------------
// 512 blocks x 256 thr; 4 rows/block; wave = 1 row; lane-halves split c.
__global__ __launch_bounds__(256) void k_proj(
    const float* __restrict__ inp, const float* __restrict__ kin,
    const float* __restrict__ vin, const float* __restrict__ W,
    const float* __restrict__ Wk,  const float* __restrict__ Wv,
    const float* __restrict__ a,
    float* __restrict__ vv, float* __restrict__ p,
    float* __restrict__ q1, float* __restrict__ q2)
{
    int tid  = threadIdx.x;
    int lane = tid & 63;
    int f    = lane & 31;
    int h    = lane >> 5;          // c-half selector
    int rl   = tid >> 6;           // 0..3
    int row  = blockIdx.x*4 + rl;  // 0..2047
    const float* xr = inp + row*64 + h*32;
    const float* kr = kin + row*64 + h*32;
    const float* vr = vin + row*64 + h*32;
    const float* Wb  = W  + (h*32)*32 + f;
    const float* Wkb = Wk + (h*32)*32 + f;
    const float* Wvb = Wv + (h*32)*32 + f;
    float ha = 0.f, ka = 0.f, va = 0.f;
    #pragma unroll
    for (int c = 0; c < 32; c++){
        float x = xr[c], k = kr[c], v = vr[c];
        ha += x * Wb [c*32];
        ka += k * Wkb[c*32];
        va += v * Wvb[c*32];
    }
    ha += __shfl_xor(ha, 32);
    ka += __shfl_xor(ka, 32);
    va += __shfl_xor(va, 32);
    if (h == 0) vv[row*32 + f] = va;        // j-major layout
    float a1 = a[f], a2 = a[32+f];
    float pv  = ha*(a1+a2);
    float q1v = ka*a1;
    float q2v = ka*a2;
    #pragma unroll
    for (int m = 16; m; m >>= 1){
        pv  += __shfl_xor(pv , m);
        q1v += __shfl_xor(q1v, m);
        q2v += __shfl_xor(q2v, m);
    }
    if (lane == 0){ p[row] = pv; q1[row] = q1v; q2[row] = q2v; }
}

// ---------------- K2: fused softmax + adj@vv + epilogue -----------------
// 512 blocks x 256 thr. block = (batch b, 4 rows). thread = (o, rr, js):
//   o  = tid&7        feature quad (f = o*4..o*4+3)
//   rr = (tid>>3)&3   row within block
//   js = tid>>5       j-slice of 128 (waves 0-1: j<512, waves 2-3: j>=512)
__global__ __launch_bounds__(256) void k_fused(
    const float* __restrict__ adj, const float* __restrict__ vv,
    const float* __restrict__ p,   const float* __restrict__ q1,
    const float* __restrict__ q2,  float* __restrict__ out)
{
    __shared__ float e[1024];            // softmax numerators (shared row)
    __shared__ float accred[4][4][32];   // [wave][row][feature]
    __shared__ float raccred[4][32];     // e.vv partials   [wave][feature]
    __shared__ float vsred[4][32];       // vv sum partials [wave][feature]
    __shared__ float zred[4];

    int tid = threadIdx.x;
    int b   = blockIdx.x & 1;
    int it  = blockIdx.x >> 1;        // 0..255
    int o   = tid & 7;
    int rr  = (tid >> 3) & 3;
    int js  = tid >> 5;               // 0..7
    int w   = tid >> 6;               // wave 0..3
    int i   = it*4 + rr;

    // ---- stage e[1024] + Z (scores bounded ~|2|, exp w/o max-sub safe) ----
    const float* q1b = q1 + b*1024;
    const float* q2b = q2 + b*1024;
    float zsum = 0.f;
    #pragma unroll
    for (int t = 0; t < 4; t++){
        int j  = tid*4 + t;
        float s = leaky(q1b[(2*j) & 1023] + q2b[(2*j+1) & 1023]);
        float ev = __expf(s);
        e[j] = ev;
        zsum += ev;
    }
    #pragma unroll
    for (int m = 32; m; m >>= 1) zsum += __shfl_xor(zsum, m);
    if ((tid & 63) == 0) zred[w] = zsum;
    __syncthreads();

    // ---- main loop: adj.vv + e.vv + Sum vv, 32 iters of 4 j's ----
    const float4* ap = (const float4*)(adj + i*1024 + js*128);
    const float4* ep = (const float4*)(e + js*128);
    const float*  vb = vv + b*32768 + js*128*32 + o*4;
    float4 acc  = make_float4(0.f,0.f,0.f,0.f);
    float4 racc = make_float4(0.f,0.f,0.f,0.f);
    float4 vs   = make_float4(0.f,0.f,0.f,0.f);
    #pragma unroll 4
    for (int m = 0; m < 32; m++){
        float4 a4 = ap[m];
        float4 e4 = ep[m];
        const float* v0p = vb + m*128;
        float4 v0 = *(const float4*)(v0p);
        float4 v1 = *(const float4*)(v0p + 32);
        float4 v2 = *(const float4*)(v0p + 64);
        float4 v3 = *(const float4*)(v0p + 96);
        acc.x += a4.x*v0.x; acc.y += a4.x*v0.y; acc.z += a4.x*v0.z; acc.w += a4.x*v0.w;
        acc.x += a4.y*v1.x; acc.y += a4.y*v1.y; acc.z += a4.y*v1.z; acc.w += a4.y*v1.w;
        acc.x += a4.z*v2.x; acc.y += a4.z*v2.y; acc.z += a4.z*v2.z; acc.w += a4.z*v2.w;
        acc.x += a4.w*v3.x; acc.y += a4.w*v3.y; acc.z += a4.w*v3.z; acc.w += a4.w*v3.w;
        racc.x += e4.x*v0.x; racc.y += e4.x*v0.y; racc.z += e4.x*v0.z; racc.w += e4.x*v0.w;
        racc.x += e4.y*v1.x; racc.y += e4.y*v1.y; racc.z += e4.y*v1.z; racc.w += e4.y*v1.w;
        racc.x += e4.z*v2.x; racc.y += e4.z*v2.y; racc.z += e4.z*v2.z; racc.w += e4.z*v2.w;
        racc.x += e4.w*v3.x; racc.y += e4.w*v3.y; racc.z += e4.w*v3.z; racc.w += e4.w*v3.w;
        vs.x += v0.x + v1.x + v2.x + v3.x;
        vs.y += v0.y + v1.y + v2.y + v3.y;
        vs.z += v0.z + v1.z + v2.z + v3.z;
        vs.w += v0.w + v1.w + v2.w + v3.w;
    }
    // combine js pairs within wave (lane ^ 32)
    acc.x  += __shfl_xor(acc.x, 32);  acc.y  += __shfl_xor(acc.y, 32);
    acc.z  += __shfl_xor(acc.z, 32);  acc.w  += __shfl_xor(acc.w, 32);
    racc.x += __shfl_xor(racc.x, 32); racc.y += __shfl_xor(racc.y, 32);
    racc.z += __shfl_xor(racc.z, 32); racc.w += __shfl_xor(racc.w, 32);
    vs.x   += __shfl_xor(vs.x, 32);   vs.y   += __shfl_xor(vs.y, 32);
    vs.z   += __shfl_xor(vs.z, 32);   vs.w   += __shfl_xor(vs.w, 32);
    if ((tid & 32) == 0){
        accred[w][rr][o*4+0] = acc.x;
        accred[w][rr][o*4+1] = acc.y;
        accred[w][rr][o*4+2] = acc.z;
        accred[w][rr][o*4+3] = acc.w;
        if (rr == 0){
            raccred[w][o*4+0] = racc.x; raccred[w][o*4+1] = racc.y;
            raccred[w][o*4+2] = racc.z; raccred[w][o*4+3] = racc.w;
            vsred[w][o*4+0] = vs.x; vsred[w][o*4+1] = vs.y;
            vsred[w][o*4+2] = vs.z; vsred[w][o*4+3] = vs.w;
        }
    }
    __syncthreads();

    // ---- epilogue: 128 threads = (row rr2, feature f) ----
    if (tid < 128){
        int rr2 = tid >> 5, f = tid & 31;
        float accsum = accred[0][rr2][f] + accred[1][rr2][f]
                     + accred[2][rr2][f] + accred[3][rr2][f];
        int i2 = it*4 + rr2;
        float att;
        if (i2 < 512){
            float vlo = vsred[0][f] + vsred[1][f];   // j <  512
            float vhi = vsred[2][f] + vsred[3][f];   // j >= 512
            float s0 = leaky(p[b*1024 + 2*i2]);
            float s1 = leaky(p[b*1024 + 2*i2 + 1]);
            float e0 = __expf(s0), e1 = __expf(s1);
            att = (e0*vlo + e1*vhi) / (512.f*(e0 + e1));
        } else {
            float rsum = raccred[0][f] + raccred[1][f]
                       + raccred[2][f] + raccred[3][f];
            float Z = zred[0] + zred[1] + zred[2] + zred[3];
            att = rsum / Z;
        }
        out[(b*1024 + i2)*32 + f] = leaky(0.5f*(att + accsum));
    }
}

extern "C" void kernel_launch(void* const* d_in, const int* in_sizes, int n_in,
                              void* d_out, int out_size, void* d_ws, size_t ws_size,
                              hipStream_t stream)
{
    const float* inp = (const float*)d_in[0];
    const float* kin = (const float*)d_in[1];
    const float* vin = (const float*)d_in[2];
    const float* adj = (const float*)d_in[3];
    const float* W   = (const float*)d_in[4];
    const float* Wk  = (const float*)d_in[5];
    const float* Wv  = (const float*)d_in[6];
    const float* a   = (const float*)d_in[7];
    float* out = (float*)d_out;

    float* ws  = (float*)d_ws;
    float* vv  = ws;            // 65536 floats, [b][j][f]
    float* p   = ws + 65536;    // 2048
    float* q1  = ws + 67584;    // 2048
    float* q2  = ws + 69632;    // 2048
    (void)in_sizes; (void)n_in; (void)out_size; (void)ws_size;

    hipLaunchKernelGGL(k_proj, dim3(512), dim3(256), 0, stream,
                       inp, kin, vin, W, Wk, Wv, a, vv, p, q1, q2);
    hipLaunchKernelGGL(k_fused, dim3(512), dim3(256), 0, stream,
                       adj, vv, p, q1, q2, out);
}